// Round 12
// baseline (37.693 us; speedup 1.0000x reference)
//
#include <hip/hip_runtime.h>
#include <math.h>

#define BB 32
#define LL 512
#define DD 1024
#define TT 256
#define NK 136393              // kept (s,e) pairs per batch
#define NK_LIN 131273          // off(502)
#define S_LIN 502
#define NEG_BIG  -3.0e38f      // finite stand-in for -inf
#define NEG_MASK -1.0e30f      // finite stand-in for masked logits
#define P_TOT (BB * NK)        // 4364576 (multiple of 4)
#define SC4 (P_TOT / 4)        // 1091144
#define GEMV_CNT 256           // 8 blocks/batch x 64 rows
#define MEMSET_CNT ((SC4 + 255) / 256)       // 4263
#define NP2 ((NK + 1) / 2)                   // 68197 pattern pairs
#define BND_PER_GRP ((NP2 + 255) / 256)      // 267
#define BND_CNT (BND_PER_GRP * 2)            // 534
#define PERIOD 19
#define NPER 267
#define GRID (PERIOD * NPER)                 // 5073

typedef float f4v __attribute__((ext_vector_type(4)));
typedef float f2v __attribute__((ext_vector_type(2)));

__device__ __forceinline__ int off_s(int s) {
    return (s <= S_LIN) ? s * (s + 21) / 2 : NK_LIN + (s - S_LIN) * LL;
}
__device__ __forceinline__ void invert(int k, int& s, int& e) {
    if (k >= NK_LIN) {
        const int r = k - NK_LIN;
        s = S_LIN + (r >> 9);
        e = r & 511;
    } else {
        float f = sqrtf(8.0f * (float)k + 441.0f);
        s = (int)((f - 21.0f) * 0.5f);
        if (s < 0) s = 0;
        if (s > 501) s = 501;
        while ((s + 1) * (s + 22) / 2 <= k) ++s;
        while (s * (s + 21) / 2 > k) --s;
        e = k - s * (s + 21) / 2;
    }
}

#define FMA_ROW(vv, A0, A1, A2)                                          \
    {                                                                    \
        _Pragma("unroll")                                                \
        for (int j = 0; j < 4; ++j) {                                    \
            f4v v = vv[j];                                               \
            f4v w0 = wr[j*3], w1 = wr[j*3+1], w2 = wr[j*3+2];            \
            A0 += v.x * w0.x;  A1 += v.x * w0.y;  A2 += v.x * w0.z;      \
            A0 += v.y * w0.w;  A1 += v.y * w1.x;  A2 += v.y * w1.y;      \
            A0 += v.z * w1.z;  A1 += v.z * w1.w;  A2 += v.z * w2.x;      \
            A0 += v.w * w2.y;  A1 += v.w * w2.z;  A2 += v.w * w2.w;      \
        }                                                                \
    }

// ---- ONE dispatch: [gemv+tail | score-memset(skip tails) | bounds] -------
__global__ __launch_bounds__(256) void mega(
    const float* __restrict__ text, const float* __restrict__ W,
    const float* __restrict__ bias, const int* __restrict__ mask,
    const int* __restrict__ tmap, float* __restrict__ out)
{
    const int id = blockIdx.x;
    const int q  = id / PERIOD;
    const int r  = id - q * PERIOD;
    const int t  = threadIdx.x;

    if (r == 0) {
        // ======== GEMV + fused tail: batch b, rows [r0l, r0l+wlen) ========
        if (q >= GEMV_CNT) return;
        const int b    = q >> 3;
        const int r0l  = (q & 7) << 6;            // 0..448
        const int wlen = min(74, LL - r0l);       // rows incl. 10-row halo
        const int wid  = t >> 6, lane = t & 63;

        __shared__ float sl[74], el[74], ml[74];
        __shared__ unsigned char tsw[74], tew[74];

        // W in registers, once per block (lane's fi = lane + j*64)
        const f4v* w4 = (const f4v*)W;
        f4v wr[12];
#pragma unroll
        for (int j = 0; j < 4; ++j) {
            const int fi = lane + j * 64;
            wr[j*3+0] = w4[fi*3+0]; wr[j*3+1] = w4[fi*3+1]; wr[j*3+2] = w4[fi*3+2];
        }
        const float b0 = bias[0], b1 = bias[1], b2 = bias[2];

        // 2-deep row pipeline: issue next row's loads before current reduce
        int lr = wid;
        f4v cv[4];
        if (lr < wlen) {
            const f4v* t4 = (const f4v*)(text + (size_t)(b * LL + r0l + lr) * DD);
#pragma unroll
            for (int j = 0; j < 4; ++j) cv[j] = t4[lane + j * 64];
        }
        while (lr < wlen) {
            const int nxt = lr + 4;
            f4v nv[4];
            if (nxt < wlen) {
                const f4v* t4 = (const f4v*)(text + (size_t)(b * LL + r0l + nxt) * DD);
#pragma unroll
                for (int j = 0; j < 4; ++j) nv[j] = t4[lane + j * 64];
            }
            float a0 = 0.f, a1 = 0.f, a2 = 0.f;
            FMA_ROW(cv, a0, a1, a2);
#pragma unroll
            for (int o = 32; o; o >>= 1) {
                a0 += __shfl_down(a0, o);
                a1 += __shfl_down(a1, o);
                a2 += __shfl_down(a2, o);
            }
            if (lane == 0) {
                const int m = mask[b * LL + r0l + lr];
                sl[lr] = (m == 1) ? a0 + b0 : NEG_MASK;
                el[lr] = (m == 1) ? a1 + b1 : NEG_MASK;
                ml[lr] = (m == 1) ? a2 + b2 : NEG_MASK;
            }
#pragma unroll
            for (int j = 0; j < 4; ++j) cv[j] = nv[j];
            lr = nxt;
        }

        // flags for window [r0l, r0l+wlen)
        if (t < 74) { tsw[t] = 0; tew[t] = 0; }
        __syncthreads();
        {
            int s0 = tmap[((size_t)b * TT + t) * 2 + 0];
            int e0 = tmap[((size_t)b * TT + t) * 2 + 1] - 1;
            s0 = min(max(s0, 0), LL - 1);
            e0 = min(max(e0, 0), LL - 1);
            if (s0 >= r0l && s0 < r0l + wlen) tsw[s0 - r0l] = 1;  // benign race
            if (e0 >= r0l && e0 < r0l + wlen) tew[e0 - r0l] = 1;
        }
        __syncthreads();

        // tail: 64 s-values x 11 offsets; write ALL (value or NEG_BIG)
        for (int it = t; it < 64 * 11; it += 256) {
            const int s_loc = it / 11;
            const int j     = it - s_loc * 11;
            const int s     = r0l + s_loc;
            const int e     = s + j;
            if (e >= LL) continue;
            const int e_loc = s_loc + j;
            float v = NEG_BIG;
            if (s > 0 && tsw[s_loc] && tew[e_loc]) {
                float w = 0.f;
                for (int l = s_loc; l <= e_loc; ++l) w += ml[l];
                v = sl[s_loc] + el[e_loc] + w;
                if (v < -1.0e29f) v = NEG_BIG;    // masked -> -inf in ref
            }
            out[(size_t)b * NK + off_s(s) + e] = v;
        }
        return;
    }

    if (r <= 16) {
        // ======== score memset: NEG_BIG on prefix positions (e < s) ========
        const int m = q * 16 + (r - 1);
        if (m >= MEMSET_CNT) return;
        const int gid = m * 256 + t;
        if (gid >= SC4) return;
        const int p4 = gid * 4;
        const int b  = p4 / NK;
        const int k  = p4 - b * NK;
        int s, e;
        invert(k, s, e);
        if (e + 3 < s) {                          // whole quad in-row prefix
            f4v neg = {NEG_BIG, NEG_BIG, NEG_BIG, NEG_BIG};
            *(f4v*)(out + p4) = neg;
        } else {
            int rowlen = (s <= S_LIN) ? (s + 11) : LL;
#pragma unroll
            for (int kk = 0; kk < 4; ++kk) {
                if (e < s) out[p4 + kk] = NEG_BIG;
                ++e;
                if (e >= rowlen) {
                    e = 0; ++s;
                    if (s >= LL) s = 0;           // next batch, same pattern
                    rowlen = (s <= S_LIN) ? (s + 11) : LL;
                }
            }
        }
        return;
    }

    // ======== bounds: invert pattern pair once, fan out to 16 batches ======
    const int v = q * 2 + (r - 17);
    if (v >= BND_CNT) return;
    const int g  = (v >= BND_PER_GRP) ? 1 : 0;
    const int c  = v - g * BND_PER_GRP;
    const int pp = c * 256 + t;
    if (pp >= NP2) return;
    const int p = pp * 2;
    int s, e;
    invert(p, s, e);
    int s1 = s, e1 = e + 1;
    const int rowlen = (s <= S_LIN) ? (s + 11) : LL;
    if (e1 >= rowlen) { e1 = 0; s1 = s + 1; if (s1 >= LL) s1 = 0; }
    const bool has2 = (p + 1 < NK);
    const float sf = (float)s, ef = (float)e, s1f = (float)s1, e1f = (float)e1;
    float* bp = out + (size_t)P_TOT;
#pragma unroll
    for (int j = 0; j < 16; ++j) {
        const int bb = g * 16 + j;
        const size_t base = ((size_t)bb * NK + p) * 2;   // float offset
        if (has2) {
            if ((bb & 1) == 0) {                  // (bb*NK+p) even -> 16B aligned
                f4v vv = {sf, ef, s1f, e1f};
                *(f4v*)(bp + base) = vv;
            } else {
                f2v v0 = {sf, ef}, v1 = {s1f, e1f};
                *(f2v*)(bp + base) = v0;
                *(f2v*)(bp + base + 2) = v1;
            }
        } else {
            f2v v0 = {sf, ef};
            *(f2v*)(bp + base) = v0;
        }
    }
}

extern "C" void kernel_launch(void* const* d_in, const int* in_sizes, int n_in,
                              void* d_out, int out_size, void* d_ws, size_t ws_size,
                              hipStream_t stream) {
    const float* text = (const float*)d_in[0];   // (B,L,D) f32
    const int*   mask = (const int*)d_in[1];     // (B,L) i32
    const int*   tmap = (const int*)d_in[2];     // (B,T,2) i32
    const float* W    = (const float*)d_in[3];   // (D,3) f32
    const float* bias = (const float*)d_in[4];   // (3,) f32
    float* out = (float*)d_out;

    mega<<<GRID, 256, 0, stream>>>(text, W, bias, mask, tmap, out);
}

// Round 13
// 36.500 us; speedup vs baseline: 1.0327x; 1.0327x over previous
//
#include <hip/hip_runtime.h>
#include <math.h>

#define BB 32
#define LL 512
#define DD 1024
#define TT 256
#define NK 136393              // kept (s,e) pairs per batch
#define NK_LIN 131273          // off(502)
#define S_LIN 502
#define NEG_BIG  -3.0e38f      // finite stand-in for -inf
#define NEG_MASK -1.0e30f      // finite stand-in for masked logits
#define P_TOT (BB * NK)        // 4364576 (multiple of 4)
#define SC4 (P_TOT / 4)        // 1091144
#define GEMV_CNT 512           // 16 blocks/batch x 32 rows (+10 halo)
#define MEMSET_CNT ((SC4 + 511) / 512)       // 2132
#define NP2 ((NK + 1) / 2)                   // 68197 pattern pairs
#define BND_PER_GRP ((NP2 + 511) / 512)      // 134
#define BND_CNT (BND_PER_GRP * 2)            // 268
#define PERIOD 6
#define GRID (PERIOD * GEMV_CNT)             // 3072

typedef float f4v __attribute__((ext_vector_type(4)));
typedef float f2v __attribute__((ext_vector_type(2)));

__device__ __forceinline__ int off_s(int s) {
    return (s <= S_LIN) ? s * (s + 21) / 2 : NK_LIN + (s - S_LIN) * LL;
}
__device__ __forceinline__ void invert(int k, int& s, int& e) {
    if (k >= NK_LIN) {
        const int r = k - NK_LIN;
        s = S_LIN + (r >> 9);
        e = r & 511;
    } else {
        float f = sqrtf(8.0f * (float)k + 441.0f);
        s = (int)((f - 21.0f) * 0.5f);
        if (s < 0) s = 0;
        if (s > 501) s = 501;
        while ((s + 1) * (s + 22) / 2 <= k) ++s;
        while (s * (s + 21) / 2 > k) --s;
        e = k - s * (s + 21) / 2;
    }
}

#define FMA_ROW(vv, A0, A1, A2)                                          \
    {                                                                    \
        _Pragma("unroll")                                                \
        for (int j = 0; j < 4; ++j) {                                    \
            f4v v = vv[j];                                               \
            f4v w0 = wr[j*3], w1 = wr[j*3+1], w2 = wr[j*3+2];            \
            A0 += v.x * w0.x;  A1 += v.x * w0.y;  A2 += v.x * w0.z;      \
            A0 += v.y * w0.w;  A1 += v.y * w1.x;  A2 += v.y * w1.y;      \
            A0 += v.z * w1.z;  A1 += v.z * w1.w;  A2 += v.z * w2.x;      \
            A0 += v.w * w2.y;  A1 += v.w * w2.z;  A2 += v.w * w2.w;      \
        }                                                                \
    }

// ---- ONE dispatch: [gemv+tail | score-memset(prefix only) | bounds] ------
// gemv+tail: 512-thr block per (batch, 32-row seg) + 10-row halo; 8 waves
// -> 5-6 serial rows/wave (R12 had 19 at 1 wave/SIMD: latency-starved).
__global__ __launch_bounds__(512) void mega(
    const float* __restrict__ text, const float* __restrict__ W,
    const float* __restrict__ bias, const int* __restrict__ mask,
    const int* __restrict__ tmap, float* __restrict__ out)
{
    const int id = blockIdx.x;
    const int q  = id / PERIOD;                   // 0..511
    const int r  = id - q * PERIOD;
    const int t  = threadIdx.x;

    if (r == 0) {
        // ======== GEMV + fused tail: batch b, rows [r0, r0+wlen) ========
        const int b    = q >> 4;
        const int r0   = (q & 15) << 5;           // 0..480
        const int wlen = min(42, LL - r0);        // 32 own + up to 10 halo
        const int wid  = t >> 6, lane = t & 63;

        __shared__ float sl[42], el[42], ml[42];
        __shared__ unsigned char tsw[42], tew[42];

        const f4v* w4 = (const f4v*)W;
        f4v wr[12];
#pragma unroll
        for (int j = 0; j < 4; ++j) {
            const int fi = lane + j * 64;
            wr[j*3+0] = w4[fi*3+0]; wr[j*3+1] = w4[fi*3+1]; wr[j*3+2] = w4[fi*3+2];
        }
        const float b0 = bias[0], b1 = bias[1], b2 = bias[2];

        // 2-deep row pipeline, wave-strided rows (stride 8)
        int lr = wid;
        f4v cv[4];
        if (lr < wlen) {
            const f4v* t4 = (const f4v*)(text + (size_t)(b * LL + r0 + lr) * DD);
#pragma unroll
            for (int j = 0; j < 4; ++j) cv[j] = t4[lane + j * 64];
        }
        while (lr < wlen) {
            const int nxt = lr + 8;
            f4v nv[4];
            if (nxt < wlen) {
                const f4v* t4 = (const f4v*)(text + (size_t)(b * LL + r0 + nxt) * DD);
#pragma unroll
                for (int j = 0; j < 4; ++j) nv[j] = t4[lane + j * 64];
            }
            float a0 = 0.f, a1 = 0.f, a2 = 0.f;
            FMA_ROW(cv, a0, a1, a2);
#pragma unroll
            for (int o = 32; o; o >>= 1) {
                a0 += __shfl_down(a0, o);
                a1 += __shfl_down(a1, o);
                a2 += __shfl_down(a2, o);
            }
            if (lane == 0) {
                const int m = mask[b * LL + r0 + lr];
                sl[lr] = (m == 1) ? a0 + b0 : NEG_MASK;
                el[lr] = (m == 1) ? a1 + b1 : NEG_MASK;
                ml[lr] = (m == 1) ? a2 + b2 : NEG_MASK;
            }
#pragma unroll
            for (int j = 0; j < 4; ++j) cv[j] = nv[j];
            lr = nxt;
        }

        if (t < 42) { tsw[t] = 0; tew[t] = 0; }
        __syncthreads();
        if (t < TT) {
            int s0 = tmap[((size_t)b * TT + t) * 2 + 0];
            int e0 = tmap[((size_t)b * TT + t) * 2 + 1] - 1;
            s0 = min(max(s0, 0), LL - 1);
            e0 = min(max(e0, 0), LL - 1);
            if (s0 >= r0 && s0 < r0 + wlen) tsw[s0 - r0] = 1;  // benign race
            if (e0 >= r0 && e0 < r0 + wlen) tew[e0 - r0] = 1;
        }
        __syncthreads();

        // tail: 32 own s-values x 11 offsets = 352 items, 1 per thread
        if (t < 32 * 11) {
            const int s_loc = t / 11;
            const int j     = t - s_loc * 11;
            const int s     = r0 + s_loc;
            const int e     = s + j;
            if (e < LL) {
                const int e_loc = s_loc + j;      // <= 41 < 42
                float v = NEG_BIG;
                if (s > 0 && tsw[s_loc] && tew[e_loc]) {
                    float w = 0.f;
                    for (int l = s_loc; l <= e_loc; ++l) w += ml[l];
                    v = sl[s_loc] + el[e_loc] + w;
                    if (v < -1.0e29f) v = NEG_BIG;  // masked -> -inf in ref
                }
                out[(size_t)b * NK + off_s(s) + e] = v;
            }
        }
        return;
    }

    const int u = q * (PERIOD - 1) + (r - 1);     // non-gemv linear index

    if (u < MEMSET_CNT) {
        // ======== score memset: NEG_BIG on prefix positions (e < s) ========
        const int gid = u * 512 + t;
        if (gid >= SC4) return;
        const int p4 = gid * 4;
        const int b  = p4 / NK;
        const int k  = p4 - b * NK;
        int s, e;
        invert(k, s, e);
        if (e + 3 < s) {                          // whole quad in-row prefix
            f4v neg = {NEG_BIG, NEG_BIG, NEG_BIG, NEG_BIG};
            *(f4v*)(out + p4) = neg;
        } else {
            int rowlen = (s <= S_LIN) ? (s + 11) : LL;
#pragma unroll
            for (int kk = 0; kk < 4; ++kk) {
                if (e < s) out[p4 + kk] = NEG_BIG;
                ++e;
                if (e >= rowlen) {
                    e = 0; ++s;
                    if (s >= LL) s = 0;           // next batch, same pattern
                    rowlen = (s <= S_LIN) ? (s + 11) : LL;
                }
            }
        }
        return;
    }

    // ======== bounds: invert pattern pair once, fan out to 16 batches ======
    const int v = u - MEMSET_CNT;
    if (v >= BND_CNT) return;
    const int g  = (v >= BND_PER_GRP) ? 1 : 0;
    const int c  = v - g * BND_PER_GRP;
    const int pp = c * 512 + t;
    if (pp >= NP2) return;
    const int p = pp * 2;
    int s, e;
    invert(p, s, e);
    int s1 = s, e1 = e + 1;
    const int rowlen = (s <= S_LIN) ? (s + 11) : LL;
    if (e1 >= rowlen) { e1 = 0; s1 = s + 1; if (s1 >= LL) s1 = 0; }
    const bool has2 = (p + 1 < NK);
    const float sf = (float)s, ef = (float)e, s1f = (float)s1, e1f = (float)e1;
    float* bp = out + (size_t)P_TOT;
#pragma unroll
    for (int j = 0; j < 16; ++j) {
        const int bb = g * 16 + j;
        const size_t base = ((size_t)bb * NK + p) * 2;   // float offset
        if (has2) {
            if ((bb & 1) == 0) {                  // even batch -> 16B aligned
                f4v vv = {sf, ef, s1f, e1f};
                *(f4v*)(bp + base) = vv;
            } else {
                f2v v0 = {sf, ef}, v1 = {s1f, e1f};
                *(f2v*)(bp + base) = v0;
                *(f2v*)(bp + base + 2) = v1;
            }
        } else {
            f2v v0 = {sf, ef};
            *(f2v*)(bp + base) = v0;
        }
    }
}

extern "C" void kernel_launch(void* const* d_in, const int* in_sizes, int n_in,
                              void* d_out, int out_size, void* d_ws, size_t ws_size,
                              hipStream_t stream) {
    const float* text = (const float*)d_in[0];   // (B,L,D) f32
    const int*   mask = (const int*)d_in[1];     // (B,L) i32
    const int*   tmap = (const int*)d_in[2];     // (B,T,2) i32
    const float* W    = (const float*)d_in[3];   // (D,3) f32
    const float* bias = (const float*)d_in[4];   // (3,) f32
    float* out = (float*)d_out;

    mega<<<GRID, 512, 0, stream>>>(text, W, bias, mask, tmap, out);
}

// Round 14
// 30.659 us; speedup vs baseline: 1.2294x; 1.1905x over previous
//
#include <hip/hip_runtime.h>
#include <math.h>

#define BB 32
#define LL 512
#define DD 1024
#define TT 256
#define NK 136393              // kept (s,e) pairs per batch
#define NK_LIN 131273          // off(502)
#define S_LIN 502
#define NEG_BIG  -3.0e38f      // finite stand-in for -inf
#define NEG_MASK -1.0e30f      // finite stand-in for masked logits
#define P_TOT (BB * NK)        // 4364576 (multiple of 4)
#define SC4 (P_TOT / 4)        // 1091144
#define MEMSET_BLOCKS ((SC4 + 255) / 256)    // 4263
#define BCHUNKS ((NK + 255) / 256)           // 533
#define D1_BLOCKS (MEMSET_BLOCKS + 2 * BCHUNKS)
#define TAIL_BLOCKS 512        // 16 per batch x 32 own rows (+10 halo)

typedef float f4v __attribute__((ext_vector_type(4)));
typedef float f2v __attribute__((ext_vector_type(2)));

__device__ __forceinline__ int off_s(int s) {
    return (s <= S_LIN) ? s * (s + 21) / 2 : NK_LIN + (s - S_LIN) * LL;
}

// ---- d1: PURE WRITE stream (zero VALU): memset + bounds fan-out ----------
__global__ __launch_bounds__(256) void write_kernel(float* __restrict__ out)
{
    const int id = blockIdx.x;
    const int t  = threadIdx.x;

    if (id < MEMSET_BLOCKS) {
        const int i = id * 256 + t;
        if (i < SC4) {
            f4v neg = {NEG_BIG, NEG_BIG, NEG_BIG, NEG_BIG};
            ((f4v*)out)[i] = neg;
        }
        return;
    }

    // bounds: invert pattern position once, fan out to 16 batches
    const int q = id - MEMSET_BLOCKS;
    const int g = (q >= BCHUNKS) ? 1 : 0;
    const int c = q - g * BCHUNKS;
    const int p = c * 256 + t;
    if (p >= NK) return;
    int s, e;
    if (p >= NK_LIN) {
        const int rr = p - NK_LIN;
        s = S_LIN + (rr >> 9);
        e = rr & 511;
    } else {
        float f = sqrtf(8.0f * (float)p + 441.0f);
        s = (int)((f - 21.0f) * 0.5f);
        if (s < 0) s = 0;
        if (s > 501) s = 501;
        while ((s + 1) * (s + 22) / 2 <= p) ++s;
        while (s * (s + 21) / 2 > p) --s;
        e = p - s * (s + 21) / 2;
    }
    f2v v = {(float)s, (float)e};
    f2v* bp = (f2v*)(out + (size_t)P_TOT);
#pragma unroll
    for (int j = 0; j < 16; ++j) {
        const int b = g * 16 + j;
        bp[(size_t)b * NK + p] = v;               // lane-contiguous 512B/wave
    }
}

// ---- d2: tail-only. Block = (batch, 32-row seg); recompute 42-row logits
// wave-per-row (8 waves, 3-deep rolling pipeline, static buffers), then
// write the <=11 data-dependent scores per row over d1's memset. ----------
#define LOADR(buf, lr)                                                    \
    if ((lr) < wlen) {                                                    \
        const f4v* t4 = (const f4v*)(text + (size_t)(rowg0 + (lr)) * DD); \
        _Pragma("unroll")                                                 \
        for (int j = 0; j < 4; ++j) buf[j] = t4[lane + j * 64];           \
    }

#define REDUCER(buf, lr)                                                  \
    if ((lr) < wlen) {                                                    \
        float a0 = 0.f, a1 = 0.f, a2 = 0.f;                               \
        _Pragma("unroll")                                                 \
        for (int j = 0; j < 4; ++j) {                                     \
            f4v v = buf[j];                                               \
            f4v w0 = wr[j*3], w1 = wr[j*3+1], w2 = wr[j*3+2];             \
            a0 += v.x * w0.x;  a1 += v.x * w0.y;  a2 += v.x * w0.z;       \
            a0 += v.y * w0.w;  a1 += v.y * w1.x;  a2 += v.y * w1.y;       \
            a0 += v.z * w1.z;  a1 += v.z * w1.w;  a2 += v.z * w2.x;       \
            a0 += v.w * w2.y;  a1 += v.w * w2.z;  a2 += v.w * w2.w;       \
        }                                                                 \
        _Pragma("unroll")                                                 \
        for (int o = 32; o; o >>= 1) {                                    \
            a0 += __shfl_down(a0, o);                                     \
            a1 += __shfl_down(a1, o);                                     \
            a2 += __shfl_down(a2, o);                                     \
        }                                                                 \
        if (lane == 0) {                                                  \
            const int m = mask[rowg0 + (lr)];                             \
            sl[lr] = (m == 1) ? a0 + b0 : NEG_MASK;                       \
            el[lr] = (m == 1) ? a1 + b1 : NEG_MASK;                       \
            ml[lr] = (m == 1) ? a2 + b2 : NEG_MASK;                       \
        }                                                                 \
    }

__global__ __launch_bounds__(512) void tail_kernel(
    const float* __restrict__ text, const float* __restrict__ W,
    const float* __restrict__ bias, const int* __restrict__ mask,
    const int* __restrict__ tmap, float* __restrict__ out)
{
    const int q    = blockIdx.x;                  // 0..511
    const int b    = q >> 4;
    const int r0   = (q & 15) << 5;               // 0..480
    const int wlen = min(42, LL - r0);            // 32 own + up to 10 halo
    const int rowg0 = b * LL + r0;
    const int t    = threadIdx.x;
    const int wid  = t >> 6, lane = t & 63;

    __shared__ float sl[42], el[42], ml[42];
    __shared__ unsigned char tsw[42], tew[42];

    const f4v* w4 = (const f4v*)W;
    f4v wr[12];
#pragma unroll
    for (int j = 0; j < 4; ++j) {
        const int fi = lane + j * 64;
        wr[j*3+0] = w4[fi*3+0]; wr[j*3+1] = w4[fi*3+1]; wr[j*3+2] = w4[fi*3+2];
    }
    const float b0 = bias[0], b1 = bias[1], b2 = bias[2];

    // wave w owns local rows w, w+8, ..., w+40 (max 6). 3-deep rolling
    // pipeline, statically named buffers (no dynamic indexing -> registers).
    f4v bufA[4], bufB[4], bufC[4];
    LOADR(bufA, wid);
    LOADR(bufB, wid + 8);
    LOADR(bufC, wid + 16);
    REDUCER(bufA, wid);        LOADR(bufA, wid + 24);
    REDUCER(bufB, wid + 8);    LOADR(bufB, wid + 32);
    REDUCER(bufC, wid + 16);   LOADR(bufC, wid + 40);
    REDUCER(bufA, wid + 24);
    REDUCER(bufB, wid + 32);
    REDUCER(bufC, wid + 40);

    if (t < 42) { tsw[t] = 0; tew[t] = 0; }
    __syncthreads();
    if (t < TT) {
        int s0 = tmap[((size_t)b * TT + t) * 2 + 0];
        int e0 = tmap[((size_t)b * TT + t) * 2 + 1] - 1;
        s0 = min(max(s0, 0), LL - 1);
        e0 = min(max(e0, 0), LL - 1);
        if (s0 >= r0 && s0 < r0 + wlen) tsw[s0 - r0] = 1;   // benign race
        if (e0 >= r0 && e0 < r0 + wlen) tew[e0 - r0] = 1;
    }
    __syncthreads();

    // 32 own s-values x 11 offsets = 352 items, 1 per thread
    if (t < 32 * 11) {
        const int s_loc = t / 11;
        const int j     = t - s_loc * 11;
        const int s     = r0 + s_loc;
        const int e     = s + j;
        if (e < LL) {
            const int e_loc = s_loc + j;          // <= 41
            float v = NEG_BIG;
            if (s > 0 && tsw[s_loc] && tew[e_loc]) {
                float w = 0.f;
                for (int l = s_loc; l <= e_loc; ++l) w += ml[l];
                v = sl[s_loc] + el[e_loc] + w;
                if (v < -1.0e29f) v = NEG_BIG;    // masked -> -inf in ref
            }
            out[(size_t)b * NK + off_s(s) + e] = v;   // over d1's memset
        }
    }
}

extern "C" void kernel_launch(void* const* d_in, const int* in_sizes, int n_in,
                              void* d_out, int out_size, void* d_ws, size_t ws_size,
                              hipStream_t stream) {
    const float* text = (const float*)d_in[0];   // (B,L,D) f32
    const int*   mask = (const int*)d_in[1];     // (B,L) i32
    const int*   tmap = (const int*)d_in[2];     // (B,T,2) i32
    const float* W    = (const float*)d_in[3];   // (D,3) f32
    const float* bias = (const float*)d_in[4];   // (3,) f32
    float* out = (float*)d_out;

    write_kernel<<<D1_BLOCKS, 256, 0, stream>>>(out);
    tail_kernel<<<TAIL_BLOCKS, 512, 0, stream>>>(text, W, bias, mask, tmap, out);
}